// Round 9
// baseline (409.732 us; speedup 1.0000x reference)
//
#include <hip/hip_runtime.h>
#include <hip/hip_bf16.h>

#define NN 8192
#define INC 128
#define HC 256          // HEADS*OUT
#define NPB 16          // nodes per block in k_h_p
#define NGRP (NN / NPB) // 512 blocks
#define SCALE_BLOCKS 512
#define MAXDEG 32       // rows built from 32 draws -> <=32 distinct edges/node

// K1: h = x@W+b ; ps/pd = h@att1 halves (16 nodes/block, register-blocked);
// also builds CSR row offsets from the src-sorted edge list.
__global__ __launch_bounds__(256) void k_h_p(
    const float* __restrict__ x, const float* __restrict__ W,
    const float* __restrict__ bias, const float* __restrict__ att1,
    const int* __restrict__ ei, float* __restrict__ h,
    float* __restrict__ ps, float* __restrict__ pd,
    int* __restrict__ offs, int E) {
  int t = threadIdx.x;
  int n0 = blockIdx.x * NPB;
  // CSR build (independent of matmul; overlaps with staging)
  for (int e = blockIdx.x * 256 + t; e < E; e += NGRP * 256) {
    if (e == 0) offs[0] = 0;
    else { int s1 = ei[e]; if (s1 != ei[e - 1]) offs[s1] = e; }
    if (e == E - 1) offs[NN] = E;
  }
  __shared__ float xs[NPB * INC];   // 8 KB
  __shared__ float hs[NPB * HC];    // 16 KB
  {
    const float4* xin = (const float4*)(x + (size_t)n0 * INC);
    ((float4*)xs)[t] = xin[t];
    ((float4*)xs)[t + 256] = xin[t + 256];
  }
  __syncthreads();
  {
    float acc[NPB];
    float b = bias[t];
    #pragma unroll
    for (int n = 0; n < NPB; ++n) acc[n] = b;
    #pragma unroll 2
    for (int d = 0; d < INC; ++d) {
      float w = W[d * HC + t];
      #pragma unroll
      for (int n = 0; n < NPB; ++n) acc[n] += xs[n * INC + d] * w;  // broadcast
    }
    #pragma unroll
    for (int n = 0; n < NPB; ++n) {
      h[((size_t)(n0 + n)) * HC + t] = acc[n];
      hs[n * HC + t] = acc[n];
    }
  }
  __syncthreads();
  int f = t & 63, sel = t >> 6;
  int hh = sel & 1, isdst = sel >> 1;
  const float* a1 = att1 + (isdst ? 128 * 64 : 0) + f;
  float p[NPB];
  #pragma unroll
  for (int n = 0; n < NPB; ++n) p[n] = 0.f;
  #pragma unroll 2
  for (int d = 0; d < 128; ++d) {
    float w = a1[d * 64];
    #pragma unroll
    for (int n = 0; n < NPB; ++n) p[n] += hs[n * HC + hh * 128 + d] * w;
  }
  float* dp = isdst ? pd : ps;
  #pragma unroll
  for (int n = 0; n < NPB; ++n)
    dp[((size_t)(n0 + n)) * 128 + hh * 64 + f] = p[n];
}

// K2: fused score+exp+aggregate for node n (one block), two phases:
//  P1: evl[hh][i] = exp(score(edge i, hh))       (pd gathers, addresses LDS-ready)
//  P2: raw[n][c] += evl * h[dst][c]              (independent float4 gathers)
// part[n][hh] = sum_i evl -- normalization deferred to k_scale (no atomics).
// Non-stable softmax: |score| = O(10) -> f32-safe, identical result.
__global__ __launch_bounds__(256) void k_agg(
    const float* __restrict__ h, const float* __restrict__ ps,
    const float* __restrict__ pd, const int* __restrict__ ei,
    const float* __restrict__ att2, const int* __restrict__ offs,
    float* __restrict__ raw, float* __restrict__ part, int E) {
  int n = blockIdx.x, t = threadIdx.x;
  __shared__ float psl[128];
  __shared__ float w2l[64];
  __shared__ int   dstl[MAXDEG];
  __shared__ float evl[2][MAXDEG];
  __shared__ float red[4 * HC];   // per-wave accumulators
  __shared__ float rs[4][2];      // per-wave head sums
  if (t < 128) psl[t] = ps[(size_t)n * 128 + t];
  if (t < 64) w2l[t] = att2[t];
  int lo = offs[n], hi = offs[n + 1];
  int m = hi - lo;                 // <= MAXDEG
  if (t < m) dstl[t] = ei[E + lo + t];
  __syncthreads();
  int wid = t >> 6, lane = t & 63;
  int head = lane >> 5, j = lane & 31;
  // ---- phase 1: scores (wave wid handles edges wid, wid+4, ...) ----
  float pa = psl[head * 64 + j * 2], pb = psl[head * 64 + j * 2 + 1];
  float wa = w2l[j * 2], wb = w2l[j * 2 + 1];
  float rsum = 0.f;
  #pragma unroll 2
  for (int i = wid; i < m; i += 4) {
    int dst = dstl[i];                           // LDS, address ready
    float2 pdv = *(const float2*)&pd[(size_t)dst * 128 + head * 64 + j * 2];
    float v0 = pa + pdv.x; v0 = v0 > 0.f ? v0 : 0.01f * v0;
    float v1 = pb + pdv.y; v1 = v1 > 0.f ? v1 : 0.01f * v1;
    float sc = v0 * wa + v1 * wb;
    sc += __shfl_xor(sc, 1);  sc += __shfl_xor(sc, 2);  sc += __shfl_xor(sc, 4);
    sc += __shfl_xor(sc, 8);  sc += __shfl_xor(sc, 16); // sum within 32-half
    float ev = __expf(sc);
    if (j == 0) { evl[head][i] = ev; rsum += ev; }
  }
  if (j == 0) rs[wid][head] = rsum;
  __syncthreads();
  // ---- phase 2: aggregation; lane covers cols lane*4..lane*4+3 (head = lane>>5) ----
  float4 acc = {0.f, 0.f, 0.f, 0.f};
  #pragma unroll 4
  for (int i = wid; i < m; i += 4) {
    float ev = evl[head][i];                     // LDS broadcast
    float4 h4 = *(const float4*)&h[(size_t)dstl[i] * HC + lane * 4];
    acc.x += ev * h4.x; acc.y += ev * h4.y; acc.z += ev * h4.z; acc.w += ev * h4.w;
  }
  ((float4*)red)[wid * 64 + lane] = acc;         // red[wid*256 + col]
  __syncthreads();
  float tot = red[t] + red[HC + t] + red[2 * HC + t] + red[3 * HC + t];
  raw[(size_t)n * HC + t] = tot;
  if (t < 2)
    part[n * 2 + t] = rs[0][t] + rs[1][t] + rs[2][t] + rs[3][t];
}

// K3: reduce part[8192][2] -> per-head sums (every block, L2-hot), then
//   out[n][d] = 0.5*(raw[n][d]*inv0 + raw[n][128+d]*inv1)
__global__ __launch_bounds__(256) void k_scale(
    const float* __restrict__ raw, const float* __restrict__ part,
    float* __restrict__ out) {
  int t = threadIdx.x;
  float s0 = 0.f, s1 = 0.f;
  #pragma unroll 4
  for (int k = 0; k < 32; ++k) {
    float2 p = ((const float2*)part)[t + 256 * k];
    s0 += p.x; s1 += p.y;
  }
  #pragma unroll
  for (int off = 1; off <= 32; off <<= 1) {
    s0 += __shfl_xor(s0, off);
    s1 += __shfl_xor(s1, off);
  }
  __shared__ float ws0[4], ws1[4];
  if ((t & 63) == 0) { ws0[t >> 6] = s0; ws1[t >> 6] = s1; }
  __syncthreads();
  float inv0 = 1.f / (ws0[0] + ws0[1] + ws0[2] + ws0[3]);
  float inv1 = 1.f / (ws1[0] + ws1[1] + ws1[2] + ws1[3]);
  const float4* r4 = (const float4*)raw;
  float4* o4 = (float4*)out;
  int idx = blockIdx.x * 256 + t;
  #pragma unroll
  for (int rep = 0; rep < 2; ++rep, idx += SCALE_BLOCKS * 256) {
    int nn = idx >> 5, c4 = idx & 31;          // 32 float4 per 128-col out row
    float4 a = r4[nn * 64 + c4];               // head0 cols
    float4 b = r4[nn * 64 + 32 + c4];          // head1 cols
    float4 o;
    o.x = 0.5f * (a.x * inv0 + b.x * inv1);
    o.y = 0.5f * (a.y * inv0 + b.y * inv1);
    o.z = 0.5f * (a.z * inv0 + b.z * inv1);
    o.w = 0.5f * (a.w * inv0 + b.w * inv1);
    o4[idx] = o;
  }
}

extern "C" void kernel_launch(void* const* d_in, const int* in_sizes, int n_in,
                              void* d_out, int out_size, void* d_ws, size_t ws_size,
                              hipStream_t stream) {
  const float* x    = (const float*)d_in[0];
  // d_in[1] = theta: UNUSED by the reference (edge list precomputed)
  const float* W    = (const float*)d_in[2];
  const float* bias = (const float*)d_in[3];
  const float* att1 = (const float*)d_in[4];
  const float* att2 = (const float*)d_in[5];
  const int* ei = (const int*)d_in[6];
  int E = in_sizes[6] / 2;
  float* out = (float*)d_out;

  float* ws = (float*)d_ws;
  float* h    = ws;                         // 8 MB
  float* ps   = h  + (size_t)NN * HC;       // 4 MB
  float* pd   = ps + (size_t)NN * 128;      // 4 MB
  float* raw  = pd + (size_t)NN * 128;      // 8 MB
  float* part = raw + (size_t)NN * HC;      // 64 KB
  int*   offs = (int*)(part + (size_t)NN * 2);  // NN+1 ints

  k_h_p<<<NGRP, 256, 0, stream>>>(x, W, bias, att1, ei, h, ps, pd, offs, E);
  k_agg<<<NN, 256, 0, stream>>>(h, ps, pd, ei, att2, offs, raw, part, E);
  k_scale<<<SCALE_BLOCKS, 256, 0, stream>>>(raw, part, out);
}

// Round 10
// 378.460 us; speedup vs baseline: 1.0826x; 1.0826x over previous
//
#include <hip/hip_runtime.h>
#include <hip/hip_bf16.h>

#define NN 8192
#define INC 128
#define HC 256          // HEADS*OUT
#define NPB 16          // nodes per block in k_h_p
#define NGRP (NN / NPB) // 512 blocks
#define APB 4           // nodes per block in k_agg (one wave per node)
#define AGRID (NN / APB)
#define SCALE_BLOCKS 512
#define MAXDEG 32       // rows built from 32 draws -> <=32 distinct edges/node

// K1: h = x@W+b ; ps/pd = h@att1 halves. 16 nodes/block.
// Thread tile: 4 nodes (ng = wave id -> wave-uniform LDS broadcasts) x 4 cols.
// Also builds CSR row offsets from the src-sorted edge list.
__global__ __launch_bounds__(256) void k_h_p(
    const float* __restrict__ x, const float* __restrict__ W,
    const float* __restrict__ bias, const float* __restrict__ att1,
    const int* __restrict__ ei, float* __restrict__ h,
    float* __restrict__ ps, float* __restrict__ pd,
    int* __restrict__ offs, int E) {
  int t = threadIdx.x;
  int n0 = blockIdx.x * NPB;
  // CSR build (overlaps with staging)
  for (int e = blockIdx.x * 256 + t; e < E; e += NGRP * 256) {
    if (e == 0) offs[0] = 0;
    else { int s1 = ei[e]; if (s1 != ei[e - 1]) offs[s1] = e; }
    if (e == E - 1) offs[NN] = E;
  }
  __shared__ float xs[NPB * INC];   // 8 KB, natural [n][d]
  __shared__ float hs[NPB * HC];    // 16 KB, natural [n][c]
  {
    const float4* xin = (const float4*)(x + (size_t)n0 * INC);
    ((float4*)xs)[t] = xin[t];
    ((float4*)xs)[t + 256] = xin[t + 256];
  }
  __syncthreads();
  int cg = t & 63, ng = t >> 6;     // ng == wave id (wave-uniform)
  // ---- h phase: nodes ng*4..+3, cols cg*4..+3 ----
  {
    float4 b4 = *(const float4*)&bias[cg * 4];
    float4 a0 = b4, a1 = b4, a2 = b4, a3 = b4;
    const float* xr0 = xs + (ng * 4 + 0) * INC;
    const float* xr1 = xs + (ng * 4 + 1) * INC;
    const float* xr2 = xs + (ng * 4 + 2) * INC;
    const float* xr3 = xs + (ng * 4 + 3) * INC;
    #pragma unroll 4
    for (int d = 0; d < INC; ++d) {
      float4 w4 = *(const float4*)&W[d * HC + cg * 4];   // coalesced 1KB/wave
      float x0 = xr0[d], x1 = xr1[d], x2 = xr2[d], x3 = xr3[d];  // broadcasts
      a0.x += x0 * w4.x; a0.y += x0 * w4.y; a0.z += x0 * w4.z; a0.w += x0 * w4.w;
      a1.x += x1 * w4.x; a1.y += x1 * w4.y; a1.z += x1 * w4.z; a1.w += x1 * w4.w;
      a2.x += x2 * w4.x; a2.y += x2 * w4.y; a2.z += x2 * w4.z; a2.w += x2 * w4.w;
      a3.x += x3 * w4.x; a3.y += x3 * w4.y; a3.z += x3 * w4.z; a3.w += x3 * w4.w;
    }
    float4* hb = (float4*)&hs[(ng * 4) * HC + cg * 4];
    *(float4*)&h[(size_t)(n0 + ng * 4 + 0) * HC + cg * 4] = a0;
    *(float4*)&h[(size_t)(n0 + ng * 4 + 1) * HC + cg * 4] = a1;
    *(float4*)&h[(size_t)(n0 + ng * 4 + 2) * HC + cg * 4] = a2;
    *(float4*)&h[(size_t)(n0 + ng * 4 + 3) * HC + cg * 4] = a3;
    hb[0] = a0; hb[HC / 4] = a1; hb[2 * HC / 4] = a2; hb[3 * HC / 4] = a3;
  }
  __syncthreads();
  // ---- p phase: sel = cg>>4 -> (head, isdst); f = (cg&15)*4 ----
  {
    int fg = cg & 15, sel = cg >> 4;
    int head = sel & 1, isdst = sel >> 1;
    const float* a1p = att1 + isdst * 128 * 64 + fg * 4;
    float4 p0 = {0,0,0,0}, p1 = {0,0,0,0}, p2 = {0,0,0,0}, p3 = {0,0,0,0};
    const float* hr0 = hs + (ng * 4 + 0) * HC + head * 128;
    const float* hr1 = hs + (ng * 4 + 1) * HC + head * 128;
    const float* hr2 = hs + (ng * 4 + 2) * HC + head * 128;
    const float* hr3 = hs + (ng * 4 + 3) * HC + head * 128;
    #pragma unroll 4
    for (int d = 0; d < 128; ++d) {
      float4 a4 = *(const float4*)&a1p[d * 64];
      float h0 = hr0[d], h1 = hr1[d], h2 = hr2[d], h3 = hr3[d];  // 2-addr broadcast
      p0.x += h0 * a4.x; p0.y += h0 * a4.y; p0.z += h0 * a4.z; p0.w += h0 * a4.w;
      p1.x += h1 * a4.x; p1.y += h1 * a4.y; p1.z += h1 * a4.z; p1.w += h1 * a4.w;
      p2.x += h2 * a4.x; p2.y += h2 * a4.y; p2.z += h2 * a4.z; p2.w += h2 * a4.w;
      p3.x += h3 * a4.x; p3.y += h3 * a4.y; p3.z += h3 * a4.z; p3.w += h3 * a4.w;
    }
    float* dp = isdst ? pd : ps;
    *(float4*)&dp[(size_t)(n0 + ng * 4 + 0) * 128 + head * 64 + fg * 4] = p0;
    *(float4*)&dp[(size_t)(n0 + ng * 4 + 1) * 128 + head * 64 + fg * 4] = p1;
    *(float4*)&dp[(size_t)(n0 + ng * 4 + 2) * 128 + head * 64 + fg * 4] = p2;
    *(float4*)&dp[(size_t)(n0 + ng * 4 + 3) * 128 + head * 64 + fg * 4] = p3;
  }
}

// K2: fused score+exp+aggregate; ONE WAVE PER NODE (4 nodes/block).
// P1: evl[i] = exp(score(edge i, head)); P2: raw[n][c] = sum_i evl*h[dst_i][c].
// part[n][hh] = sum_i evl -- normalization deferred to k_scale (no atomics).
// Non-stable softmax: |score| = O(10) -> f32-safe, identical result.
__global__ __launch_bounds__(256) void k_agg(
    const float* __restrict__ h, const float* __restrict__ ps,
    const float* __restrict__ pd, const int* __restrict__ ei,
    const float* __restrict__ att2, const int* __restrict__ offs,
    float* __restrict__ raw, float* __restrict__ part, int E) {
  int t = threadIdx.x, wid = t >> 6, lane = t & 63;
  int n = blockIdx.x * APB + wid;
  __shared__ float w2l[64];
  __shared__ int   dstl[APB][MAXDEG];
  __shared__ float evl[APB][2][MAXDEG];
  if (t < 64) w2l[t] = att2[t];
  int lo = offs[n], hi = offs[n + 1];
  int m = hi - lo;                       // <= MAXDEG
  if (lane < m) dstl[wid][lane] = ei[E + lo + lane];
  __syncthreads();
  int head = lane >> 5, j = lane & 31;
  float2 psv = *(const float2*)&ps[(size_t)n * 128 + head * 64 + j * 2];
  float wa = w2l[j * 2], wb = w2l[j * 2 + 1];
  float rsum = 0.f;
  #pragma unroll 4
  for (int i = 0; i < m; ++i) {
    int dst = dstl[wid][i];
    float2 pdv = *(const float2*)&pd[(size_t)dst * 128 + head * 64 + j * 2];
    float v0 = psv.x + pdv.x; v0 = v0 > 0.f ? v0 : 0.01f * v0;
    float v1 = psv.y + pdv.y; v1 = v1 > 0.f ? v1 : 0.01f * v1;
    float sc = v0 * wa + v1 * wb;
    sc += __shfl_xor(sc, 1);  sc += __shfl_xor(sc, 2);  sc += __shfl_xor(sc, 4);
    sc += __shfl_xor(sc, 8);  sc += __shfl_xor(sc, 16);   // sum within 32-half
    float ev = __expf(sc);
    if (j == 0) { evl[wid][head][i] = ev; rsum += ev; }
  }
  if (j == 0) part[n * 2 + head] = rsum;
  __syncthreads();
  // P2: lane covers cols lane*4..+3 (col>>7 == lane>>5 == head); 2 acc chains
  const float* evh = evl[wid][head];
  float4 a0 = {0,0,0,0}, a1 = {0,0,0,0};
  int i = 0;
  for (; i + 2 <= m; i += 2) {
    float e0 = evh[i], e1 = evh[i + 1];
    float4 h0 = *(const float4*)&h[(size_t)dstl[wid][i] * HC + lane * 4];
    float4 h1 = *(const float4*)&h[(size_t)dstl[wid][i + 1] * HC + lane * 4];
    a0.x += e0 * h0.x; a0.y += e0 * h0.y; a0.z += e0 * h0.z; a0.w += e0 * h0.w;
    a1.x += e1 * h1.x; a1.y += e1 * h1.y; a1.z += e1 * h1.z; a1.w += e1 * h1.w;
  }
  if (i < m) {
    float e0 = evh[i];
    float4 h0 = *(const float4*)&h[(size_t)dstl[wid][i] * HC + lane * 4];
    a0.x += e0 * h0.x; a0.y += e0 * h0.y; a0.z += e0 * h0.z; a0.w += e0 * h0.w;
  }
  float4 res;
  res.x = a0.x + a1.x; res.y = a0.y + a1.y;
  res.z = a0.z + a1.z; res.w = a0.w + a1.w;
  *(float4*)&raw[(size_t)n * HC + lane * 4] = res;
}

// K3: reduce part[8192][2] -> per-head sums (every block, L2-hot), then
//   out[n][d] = 0.5*(raw[n][d]*inv0 + raw[n][128+d]*inv1)
__global__ __launch_bounds__(256) void k_scale(
    const float* __restrict__ raw, const float* __restrict__ part,
    float* __restrict__ out) {
  int t = threadIdx.x;
  float s0 = 0.f, s1 = 0.f;
  #pragma unroll 4
  for (int k = 0; k < 32; ++k) {
    float2 p = ((const float2*)part)[t + 256 * k];
    s0 += p.x; s1 += p.y;
  }
  #pragma unroll
  for (int off = 1; off <= 32; off <<= 1) {
    s0 += __shfl_xor(s0, off);
    s1 += __shfl_xor(s1, off);
  }
  __shared__ float ws0[4], ws1[4];
  if ((t & 63) == 0) { ws0[t >> 6] = s0; ws1[t >> 6] = s1; }
  __syncthreads();
  float inv0 = 1.f / (ws0[0] + ws0[1] + ws0[2] + ws0[3]);
  float inv1 = 1.f / (ws1[0] + ws1[1] + ws1[2] + ws1[3]);
  const float4* r4 = (const float4*)raw;
  float4* o4 = (float4*)out;
  int idx = blockIdx.x * 256 + t;
  #pragma unroll
  for (int rep = 0; rep < 2; ++rep, idx += SCALE_BLOCKS * 256) {
    int nn = idx >> 5, c4 = idx & 31;
    float4 a = r4[nn * 64 + c4];               // head0 cols
    float4 b = r4[nn * 64 + 32 + c4];          // head1 cols
    float4 o;
    o.x = 0.5f * (a.x * inv0 + b.x * inv1);
    o.y = 0.5f * (a.y * inv0 + b.y * inv1);
    o.z = 0.5f * (a.z * inv0 + b.z * inv1);
    o.w = 0.5f * (a.w * inv0 + b.w * inv1);
    o4[idx] = o;
  }
}

extern "C" void kernel_launch(void* const* d_in, const int* in_sizes, int n_in,
                              void* d_out, int out_size, void* d_ws, size_t ws_size,
                              hipStream_t stream) {
  const float* x    = (const float*)d_in[0];
  // d_in[1] = theta: UNUSED by the reference (edge list precomputed)
  const float* W    = (const float*)d_in[2];
  const float* bias = (const float*)d_in[3];
  const float* att1 = (const float*)d_in[4];
  const float* att2 = (const float*)d_in[5];
  const int* ei = (const int*)d_in[6];
  int E = in_sizes[6] / 2;
  float* out = (float*)d_out;

  float* ws = (float*)d_ws;
  float* h    = ws;                         // 8 MB
  float* ps   = h  + (size_t)NN * HC;       // 4 MB
  float* pd   = ps + (size_t)NN * 128;      // 4 MB
  float* raw  = pd + (size_t)NN * 128;      // 8 MB
  float* part = raw + (size_t)NN * HC;      // 64 KB
  int*   offs = (int*)(part + (size_t)NN * 2);  // NN+1 ints

  k_h_p<<<NGRP, 256, 0, stream>>>(x, W, bias, att1, ei, h, ps, pd, offs, E);
  k_agg<<<AGRID, 256, 0, stream>>>(h, ps, pd, ei, att2, offs, raw, part, E);
  k_scale<<<SCALE_BLOCKS, 256, 0, stream>>>(raw, part, out);
}